// Round 18
// baseline (1570.876 us; speedup 1.0000x reference)
//
#include <hip/hip_runtime.h>
#include <hip/hip_bf16.h>

#define B_N 4096
#define L_N 32
#define C_N 28
#define H_N 512
#define T_N 32
#define G_N 2048
// R18 = R17 with compile fix (no static array of LDS pointers; compute
// buffer address arithmetically). fp16 numerics (A hi/lo pair, W single),
// 4-buffer single-barrier deep pipeline:
// Per chunk c: vmcnt(6) [c+1 landed, c+2 in flight] -> barrier -> lgkmcnt(0) ->
// {ds_read c+1 || stage c+3 || 32 MFMA of c} SGB-interleaved. ONE barrier/chunk.
// LDS 4 x 24KB = 96KB -> 1 block/CU, grid 512 = 2 rounds.
// W column packing: gate = t&3, unit = n128*32 + (t>>2)*16 + c (in-reg epilogue).
#define CHA 34
#define CHSH 4096          // shorts per frag chunk: 8 tiles * 64 lanes * 8
#define ABLK (CHA * CHSH)
#define XS 29              // padded LDS stride for prep_x

typedef __attribute__((ext_vector_type(2))) float f32x2;
typedef __attribute__((ext_vector_type(4))) float f32x4;
typedef __attribute__((ext_vector_type(8))) short s16x8;
typedef __attribute__((ext_vector_type(8))) _Float16 f16x8;

static constexpr size_t OFF_WF = 0;                                    // Wf f16 16*ABLK
static constexpr size_t AB_ONE = (size_t)32 * ABLK * 2;                // 8.9 MB
static constexpr size_t OFF_AB = OFF_WF + (size_t)16 * ABLK * 2;
static constexpr size_t OFF_X  = OFF_AB + 2 * AB_ONE;                  // f32 [4096][32][28]
static constexpr size_t OFF_UA = OFF_X + (size_t)B_N * L_N * C_N * 4;  // f32 [4096][32]
static constexpr size_t OFF_BS = OFF_UA + (size_t)B_N * L_N * 4;       // f32 [2048]
static constexpr size_t OFF_AC = OFF_BS + 8192;                        // accW[4096][32], accO[4096][32]
static constexpr size_t ACC_HALF = (size_t)32 * B_N * 4;               // 512 KB
static constexpr size_t OFF_CS = OFF_AC + 2 * ACC_HALF;                // f32 [4096][512]
static constexpr size_t WS_NEED = OFF_CS + (size_t)B_N * H_N * 4;      // ~36 MB

__device__ __forceinline__ short hfbits(float x) {
    union { _Float16 h; short s; } v; v.h = (_Float16)x; return v.s;
}
__device__ __forceinline__ float sigmoidf_(float x) { return 1.f / (1.f + __expf(-x)); }
__device__ __forceinline__ float tanhf_(float x) {
    float ax = fabsf(x), e = __expf(-2.f * ax);
    float t = (1.f - e) / (1.f + e);
    return x < 0.f ? -t : t;
}

__global__ __launch_bounds__(256) void fill_out(float* out, float v) {
    int i = blockIdx.x * 256 + threadIdx.x;
    if (i < B_N * 32) out[i] = v;
}

// ---------------- prep_x: x-in-registers + stencil shuffles + scalar weights ----------------
__global__ __launch_bounds__(256) void prep_x(const float* __restrict__ input,
                       const float* __restrict__ mask,
                       const float* __restrict__ w1, const float* __restrict__ b1,
                       const float* __restrict__ cw, const float* __restrict__ cb,
                       float* __restrict__ x, float* __restrict__ ua)
{
    __shared__ float sin[8 * L_N * XS];
    __shared__ float sxb[8 * L_N * XS];
    const float* src = input + (size_t)blockIdx.x * (8 * L_N * C_N);
    for (int i = threadIdx.x; i < 8 * L_N * C_N; i += 256) {
        int lr = i / (L_N * C_N);
        int rem = i - lr * (L_N * C_N);
        int l = rem / C_N, c = rem - l * C_N;
        sin[lr * (L_N * XS) + l * XS + c] = src[i];
    }
    __syncthreads();

    int idx = blockIdx.x * 256 + threadIdx.x;
    int l = idx & 31;
    int wv = threadIdx.x >> 5;
    const float* inb = sin + wv * (L_N * XS);
    float m = mask[idx];

    float x0r[C_N], xm1[C_N], xp1[C_N];
    #pragma unroll
    for (int i = 0; i < C_N; ++i) x0r[i] = inb[l * XS + i];
    #pragma unroll
    for (int i = 0; i < C_N; ++i) {
        float up = __shfl_up(x0r[i], 1, 32);
        float dn = __shfl_down(x0r[i], 1, 32);
        xm1[i] = (l > 0)  ? up : 0.f;
        xp1[i] = (l < 31) ? dn : 0.f;
    }

    float uacc = 0.f;
    float* sxrow = sxb + wv * (L_N * XS) + l * XS;
    #pragma unroll 2
    for (int o = 0; o < C_N; ++o) {
        const float* wo = w1 + o * (C_N * 3);   // wave-uniform -> s_load
        float y0 = b1[o], y1 = 0.f, y2 = 0.f;
        #pragma unroll
        for (int i = 0; i < C_N; ++i) {
            y0 += wo[i * 3 + 0] * xm1[i];
            y1 += wo[i * 3 + 1] * x0r[i];
            y2 += wo[i * 3 + 2] * xp1[i];
        }
        float y = (y0 + y1 + y2) * m;
        float e = (y > 0.f) ? y : (__expf(y) - 1.f);
        float xv = e + inb[l * XS + o];
        sxrow[o] = xv;
        uacc += xv * cw[o];
    }
    ua[idx] = (uacc + cb[0]) * m;
    __syncthreads();
    float* xdst = x + (size_t)blockIdx.x * (8 * L_N * C_N);
    for (int i = threadIdx.x; i < 8 * L_N * C_N; i += 256) {
        int lr = i / (L_N * C_N);
        int rem = i - lr * (L_N * C_N);
        int l2 = rem / C_N, c = rem - l2 * C_N;
        xdst[i] = sxb[lr * (L_N * XS) + l2 * XS + c];
    }
}

// ---------------- prep_wf: frag-major SINGLE-fp16 weights, gate-in-tile packing ----------------
__global__ __launch_bounds__(256) void prep_wf(const float* __restrict__ w_ih,
                                               const float* __restrict__ w_hh,
                                               short* __restrict__ Wf)
{
    int blk = blockIdx.x;                  // 16*17
    int n128 = blk / 17, c = blk % 17;
    int kbase = c * 32;
    short* dst = Wf + ((size_t)n128 * CHA + c) * CHSH;
    for (int g = threadIdx.x; g < 512; g += 256) {
        int j = g >> 6, lane = g & 63;
        int gate = j & 3;
        int unit = n128 * 32 + (j >> 2) * 16 + (lane & 15);
        int srow = gate * H_N + unit;
        int kg = lane >> 4;
        s16x8 out;
        #pragma unroll
        for (int b2 = 0; b2 < 8; ++b2) {
            int k = kbase + kg * 8 + b2;
            float v = 0.f;
            if (k < 512) v = w_hh[(size_t)srow * H_N + k];
            else if (k < 540) v = w_ih[srow * C_N + (k - 512)];
            out[b2] = hfbits(v);
        }
        *(s16x8*)(dst + g * 8) = out;
    }
}

__global__ void prep_bs(const float* __restrict__ b_ih, const float* __restrict__ b_hh,
                        float* __restrict__ bsum)
{
    int p = blockIdx.x * 256 + threadIdx.x;
    if (p < G_N) {
        int unit = p >> 2, gate = p & 3;
        bsum[p] = b_ih[gate * H_N + unit] + b_hh[gate * H_N + unit];
    }
}

__global__ void prep_zero(unsigned int* __restrict__ a32, float* __restrict__ cst,
                          float* __restrict__ acc)
{
    int idx = blockIdx.x * blockDim.x + threadIdx.x;
    if (idx < B_N * 1088) a32[idx] = 0u;
    if (idx < B_N * H_N) cst[idx] = 0.f;
    if (idx < 2 * 32 * B_N) acc[idx] = 0.f;
}

// ---------------- params ----------------
struct RParams {
    const float* mask;
    const float* bias_mat;
    const float* fc1_w;
    const float* fc1_b;
    const float* conv2_w;
    const float* conv2_b;
    const short* Wf;
    const short* Ain;
    short* Aout;
    const float* x;
    const float* ua;
    const float* bsum;
    float* accW;           // [4096][32] slot = n*2+wn
    float* accO;           // [4096][32]
    float* cstate;
    float* out;
};

// ---------------- ctx_step: sum 32 partial slots; softmax+context (LDS-staged x) ----------------
__global__ __launch_bounds__(256) void ctx_step(RParams P, int t)
{
    __shared__ float sx[4][L_N * C_N];

    const int lane = threadIdx.x & 63;
    const int wave = threadIdx.x >> 6;
    const int row  = blockIdx.x * 4 + wave;

    f32x2 st[7];
    const float* xrow = P.x + (size_t)row * (L_N * C_N);
    #pragma unroll
    for (int q = 0; q < 7; ++q) st[q] = *(const f32x2*)(xrow + (q * 64 + lane) * 2);

    float v = (lane < 32) ? P.accW[row * 32 + lane] : P.accO[row * 32 + (lane - 32)];
    #pragma unroll
    for (int off = 1; off <= 16; off <<= 1) v += __shfl_xor(v, off);
    float aW = __shfl(v, 0);
    float aO = __shfl(v, 32);

    if (t > 0 && lane == 0)
        P.out[row * T_N + (t - 1)] = (aO + P.conv2_b[0]) * P.mask[row * L_N + (t - 1)];

    if (t < T_N) {
        float w_a = aW + P.fc1_b[0];
        int l32 = lane & 31;
        float e = P.ua[row * L_N + l32] + w_a;
        e = (e > 0.f) ? e : 0.01f * e;
        e += P.bias_mat[row * L_N + l32];
        float mx = e;
        #pragma unroll
        for (int off = 16; off > 0; off >>= 1) mx = fmaxf(mx, __shfl_xor(mx, off, 32));
        float pexp = __expf(e - mx);
        float ssum = pexp;
        #pragma unroll
        for (int off = 16; off > 0; off >>= 1) ssum += __shfl_xor(ssum, off, 32);
        float p = pexp / ssum;

        #pragma unroll
        for (int q = 0; q < 7; ++q)
            *(f32x2*)(&sx[wave][(q * 64 + lane) * 2]) = st[q];

        int cc = (lane < C_N) ? lane : 0;
        float ctx = 0.f;
        #pragma unroll
        for (int l = 0; l < L_N; ++l) {
            float al = __shfl(p, l);
            ctx += al * sx[wave][l * C_N + cc];
        }
        if (lane < C_N) {
            int m128 = row >> 7, mt = (row & 127) >> 4, r = row & 15;
            int flane = r + 16 * (lane >> 3);
            short* base = P.Aout + (size_t)m128 * ABLK + mt * 512 + flane * 8 + (lane & 7);
            _Float16 hi = (_Float16)ctx;
            union { _Float16 h; short s; } uh; uh.h = hi;
            base[16 * CHSH] = uh.s;
            base[33 * CHSH] = hfbits(ctx - (float)hi);
        }
    }
}

// ---------------- gemm_cell_step: M=128, 4-buffer single-barrier pipeline, fp16 ----------------
// Buffer (24KB): [A_hi 8K | A_lo 8K | W 8K]; 4 buffers rotate over chunks (c%4).
// Per chunk c: vmcnt(6) -> barrier -> lgkmcnt(0) -> {ds_read c+1 | stage c+3 | MFMA c}.
#define STG_BUF 24576

__global__ __launch_bounds__(256, 1) void gemm_cell_step(RParams P)
{
    __shared__ __align__(16) char smem[98304];

    const int tid  = threadIdx.x;
    const int lane = tid & 63;
    const int wave = tid >> 6;
    const int bid  = blockIdx.x;       // 512
    const int xg = bid & 7, gg = bid >> 3;
    const int m  = (xg >> 1) * 8 + (gg & 7);
    const int n  = (xg & 1) * 8 + (gg >> 3);
    const int wm = wave >> 1, wn = wave & 1;

    const short* Af = P.Ain + (size_t)m * ABLK;
    const short* Wg = P.Wf  + (size_t)n * ABLK;

    auto bufp = [&](int i) -> char* { return smem + i * STG_BUF; };

    auto stage = [&](char* lbuf, int kk) {
        const short* pAh = Af + (size_t)kk * CHSH;
        const short* pAl = Af + (size_t)(17 + kk) * CHSH;
        const short* pW  = Wg + (size_t)kk * CHSH;
        #pragma unroll
        for (int i = 0; i < 6; ++i) {
            int r = wave * 6 + i;
            const short* base = (r < 8)  ? (pAh + r * 512)
                              : (r < 16) ? (pAl + (r - 8) * 512)
                                         : (pW + (r - 16) * 512);
            __builtin_amdgcn_global_load_lds(
                (const __attribute__((address_space(1))) void*)(base + lane * 8),
                (__attribute__((address_space(3))) void*)(lbuf + r * 1024),
                16, 0, 0);
        }
    };

    int aoff[4], woff[4];
    #pragma unroll
    for (int i = 0; i < 4; ++i) {
        aoff[i] = ((wm * 4 + i) * 64 + lane) * 16;
        woff[i] = ((wn * 4 + i) * 64 + lane) * 16;
    }

    f32x4 acc[4][4];
    #pragma unroll
    for (int i = 0; i < 4; ++i)
        #pragma unroll
        for (int j = 0; j < 4; ++j)
            acc[i][j] = (f32x4){0.f, 0.f, 0.f, 0.f};

    // R[0..3]=A_hi, R[4..7]=A_lo, R[8..11]=W
    f16x8 R0[12], R1[12];
    auto ldfr = [&](const char* b, f16x8 (&R)[12]) {
        #pragma unroll
        for (int i = 0; i < 4; ++i) {
            R[i]     = *(const f16x8*)(b + aoff[i]);
            R[4 + i] = *(const f16x8*)(b + 8192 + aoff[i]);
            R[8 + i] = *(const f16x8*)(b + 16384 + woff[i]);
        }
    };
    auto domm = [&](f16x8 (&R)[12]) {
        #pragma unroll
        for (int i = 0; i < 4; ++i)
            #pragma unroll
            for (int j = 0; j < 4; ++j)
                acc[i][j] = __builtin_amdgcn_mfma_f32_16x16x32_f16(R[i], R[8 + j], acc[i][j], 0, 0, 0);
        #pragma unroll
        for (int i = 0; i < 4; ++i)
            #pragma unroll
            for (int j = 0; j < 4; ++j)
                acc[i][j] = __builtin_amdgcn_mfma_f32_16x16x32_f16(R[4 + i], R[8 + j], acc[i][j], 0, 0, 0);
    };

    // step: MFMA chunk c from Rc; prefetch chunk c+1 into Rn; stage chunk c+3.
    auto step = [&](int c, f16x8 (&Rc)[12], f16x8 (&Rn)[12], bool nr, bool ns) {
        asm volatile("s_waitcnt vmcnt(6)" ::: "memory");   // chunk c+1 landed; c+2 in flight
        __builtin_amdgcn_s_barrier();                      // all waves: reads of c-1 sealed; c+1 visible
        asm volatile("s_waitcnt lgkmcnt(0)" ::: "memory"); // my reads of chunk c (prev iter) done
        __builtin_amdgcn_sched_barrier(0);
        if (ns) stage(bufp((c + 3) & 3), c + 3);
        if (nr) ldfr(bufp((c + 1) & 3), Rn);
        domm(Rc);
        if (ns && nr) {
            #pragma unroll
            for (int g = 0; g < 6; ++g) {
                __builtin_amdgcn_sched_group_barrier(0x010, 1, 0);  // 1 VMEM
                __builtin_amdgcn_sched_group_barrier(0x100, 2, 0);  // 2 DS_READ
                __builtin_amdgcn_sched_group_barrier(0x008, 5, 0);  // 5 MFMA
            }
            __builtin_amdgcn_sched_group_barrier(0x008, 2, 0);      // last 2 MFMA
        } else if (nr) {
            #pragma unroll
            for (int g = 0; g < 6; ++g) {
                __builtin_amdgcn_sched_group_barrier(0x100, 2, 0);
                __builtin_amdgcn_sched_group_barrier(0x008, 5, 0);
            }
            __builtin_amdgcn_sched_group_barrier(0x008, 2, 0);
        }
        __builtin_amdgcn_sched_barrier(0);
    };

    // prologue: stage chunks 0,1,2; wait chunk 0 (1,2 in flight); read chunk 0.
    stage(bufp(0), 0);
    stage(bufp(1), 1);
    stage(bufp(2), 2);
    asm volatile("s_waitcnt vmcnt(12)" ::: "memory");
    __builtin_amdgcn_s_barrier();
    ldfr(bufp(0), R0);

    for (int c = 0; c < 14; c += 2) {
        step(c,     R0, R1, true, true);
        step(c + 1, R1, R0, true, true);
    }
    step(14, R0, R1, true, false);   // c+3=17: no stage
    step(15, R1, R0, true, false);   // reads chunk 16
    step(16, R0, R1, false, false);  // MFMA only

    // ---- epilogue (in-register LSTM: thread owns unit = n*32+wn*16+(lane&15)) ----
    __syncthreads();
    short* hasm = (short*)smem;              // hi 8KB @0, lo 8KB @8192
    {
        int u15 = lane & 15, rq = lane >> 4;
        int unit = n * 32 + wn * 16 + u15;
        float cpre[4][4];
        #pragma unroll
        for (int i = 0; i < 4; ++i)
            #pragma unroll
            for (int r = 0; r < 4; ++r)
                cpre[i][r] = P.cstate[(size_t)(m * 128 + wm * 64 + i * 16 + rq * 4 + r) * H_N + unit];
        f32x4 bsv = *(const f32x4*)(P.bsum + unit * 4);
        float f1v = P.fc1_w[unit];
        float c2v = P.conv2_w[unit];
        const int fl16 = 16 * (wn * 2 + (u15 >> 3));
        const int slot = u15 & 7;
        #pragma unroll
        for (int i = 0; i < 4; ++i) {
            #pragma unroll
            for (int r = 0; r < 4; ++r) {
                int grow = m * 128 + wm * 64 + i * 16 + rq * 4 + r;
                float pi = acc[i][0][r] + bsv.x;
                float pf = acc[i][1][r] + bsv.y;
                float pg = acc[i][2][r] + bsv.z;
                float po = acc[i][3][r] + bsv.w;
                float c = sigmoidf_(pf) * cpre[i][r] + sigmoidf_(pi) * tanhf_(pg);
                P.cstate[(size_t)grow * H_N + unit] = c;
                float h = sigmoidf_(po) * tanhf_(c);
                _Float16 hh = (_Float16)h;
                union { _Float16 hf; short s; } uh; uh.hf = hh;
                int fo = (wm * 4 + i) * 512 + (rq * 4 + r + fl16) * 8 + slot;
                hasm[fo]        = uh.s;
                hasm[4096 + fo] = hfbits(h - (float)hh);
                float wd = f1v * h, od = c2v * h;
                #pragma unroll
                for (int off = 8; off > 0; off >>= 1) {
                    wd += __shfl_xor(wd, off);
                    od += __shfl_xor(od, off);
                }
                if (u15 == 0) {
                    P.accW[(size_t)grow * 32 + (n * 2 + wn)] = wd;
                    P.accO[(size_t)grow * 32 + (n * 2 + wn)] = od;
                }
            }
        }
    }
    __syncthreads();
    short* dhi = P.Aout + (size_t)m * ABLK + (size_t)n * CHSH;
    short* dlo = P.Aout + (size_t)m * ABLK + (size_t)(17 + n) * CHSH;
    *(s16x8*)(dhi + tid * 16)     = *(const s16x8*)(hasm + tid * 16);
    *(s16x8*)(dhi + tid * 16 + 8) = *(const s16x8*)(hasm + tid * 16 + 8);
    *(s16x8*)(dlo + tid * 16)     = *(const s16x8*)(hasm + 4096 + tid * 16);
    *(s16x8*)(dlo + tid * 16 + 8) = *(const s16x8*)(hasm + 4096 + tid * 16 + 8);
}

extern "C" void kernel_launch(void* const* d_in, const int* in_sizes, int n_in,
                              void* d_out, int out_size, void* d_ws, size_t ws_size,
                              hipStream_t stream)
{
    float* out = (float*)d_out;
    if (ws_size < WS_NEED) { fill_out<<<512, 256, 0, stream>>>(out, 4000.f); return; }

    const float* input = (const float*)d_in[0];
    const float* mask  = (const float*)d_in[1];
    const float* biasm = (const float*)d_in[2];
    const float* w1    = (const float*)d_in[3];
    const float* b1    = (const float*)d_in[4];
    const float* cw    = (const float*)d_in[5];
    const float* cb    = (const float*)d_in[6];
    const float* w_ih  = (const float*)d_in[7];
    const float* w_hh  = (const float*)d_in[8];
    const float* b_ih  = (const float*)d_in[9];
    const float* b_hh  = (const float*)d_in[10];
    const float* fc1w  = (const float*)d_in[11];
    const float* fc1b  = (const float*)d_in[12];
    const float* c2w   = (const float*)d_in[13];
    const float* c2b   = (const float*)d_in[14];

    char* ws = (char*)d_ws;
    short* Wf = (short*)(ws + OFF_WF);
    short* A0 = (short*)(ws + OFF_AB);
    short* A1 = (short*)(ws + OFF_AB + AB_ONE);
    float* x    = (float*)(ws + OFF_X);
    float* ua   = (float*)(ws + OFF_UA);
    float* bsum = (float*)(ws + OFF_BS);
    float* accW = (float*)(ws + OFF_AC);
    float* accO = (float*)(ws + OFF_AC + ACC_HALF);
    float* cst  = (float*)(ws + OFF_CS);

    prep_x<<<(B_N * L_N) / 256, 256, 0, stream>>>(input, mask, w1, b1, cw, cb, x, ua);
    prep_wf<<<16 * 17, 256, 0, stream>>>(w_ih, w_hh, Wf);
    prep_bs<<<(G_N + 255) / 256, 256, 0, stream>>>(b_ih, b_hh, bsum);
    prep_zero<<<(B_N * 1088 + 255) / 256, 256, 0, stream>>>((unsigned int*)A0, cst, accW);

    RParams P;
    P.mask = mask; P.bias_mat = biasm; P.fc1_w = fc1w; P.fc1_b = fc1b;
    P.conv2_w = c2w; P.conv2_b = c2b; P.Wf = Wf;
    P.x = x; P.ua = ua; P.bsum = bsum; P.accW = accW; P.accO = accO;
    P.cstate = cst; P.out = out;

    short* bufs[2] = { A0, A1 };
    for (int t = 0; t < T_N; ++t) {
        P.Ain  = bufs[t & 1];
        P.Aout = bufs[t & 1];
        ctx_step<<<B_N / 4, 256, 0, stream>>>(P, t);
        P.Ain  = bufs[t & 1];
        P.Aout = bufs[(t + 1) & 1];
        gemm_cell_step<<<512, 256, 0, stream>>>(P);
    }
    P.Ain = bufs[T_N & 1];
    P.Aout = bufs[T_N & 1];
    ctx_step<<<B_N / 4, 256, 0, stream>>>(P, T_N);
}

// Round 19
// 1248.151 us; speedup vs baseline: 1.2586x; 1.2586x over previous
//
#include <hip/hip_runtime.h>
#include <hip/hip_bf16.h>

#define B_N 4096
#define L_N 32
#define C_N 28
#define H_N 512
#define T_N 32
#define G_N 2048
// R19 = R16 verbatim (best verified: 1225.5 us). fp16 GEMM: A hi/lo pair
// (chunks [0..16]=hi, [17..33]=lo), W single fp16 (chunks [0..16]).
// Paired k-steps: two chunks per step {24 ds_read | bar | stage next pair +
// 64 MFMA SGB-interleaved}; 9 steps. Gate-packed W -> in-register LSTM epilogue.
// Session ladder: 1609 -> 1363 (prep_x reg-stencil, in-reg epilogue, SGB)
// -> 1240 (fp16) -> 1225 (paired steps). Closed directions (measured):
// counted-vmcnt/3-buf/4-buf pipelines, M=64 tiles, ctx fusion (serial
// prologue + L2-killing fences), cooperative launch (graph-capture fail),
// W_lo drop (absmax 0.106 fail). gemm ~27us vs ~15us pipe floor is a
// latency/sync plateau at 2 blocks/CU, not a HW roofline.
#define CHA 34
#define CHSH 4096          // shorts per frag chunk: 8 tiles * 64 lanes * 8
#define ABLK (CHA * CHSH)
#define XS 29              // padded LDS stride for prep_x

typedef __attribute__((ext_vector_type(2))) float f32x2;
typedef __attribute__((ext_vector_type(4))) float f32x4;
typedef __attribute__((ext_vector_type(8))) short s16x8;
typedef __attribute__((ext_vector_type(8))) _Float16 f16x8;

static constexpr size_t OFF_WF = 0;                                    // Wf f16 16*ABLK
static constexpr size_t AB_ONE = (size_t)32 * ABLK * 2;                // 8.9 MB
static constexpr size_t OFF_AB = OFF_WF + (size_t)16 * ABLK * 2;
static constexpr size_t OFF_X  = OFF_AB + 2 * AB_ONE;                  // f32 [4096][32][28]
static constexpr size_t OFF_UA = OFF_X + (size_t)B_N * L_N * C_N * 4;  // f32 [4096][32]
static constexpr size_t OFF_BS = OFF_UA + (size_t)B_N * L_N * 4;       // f32 [2048]
static constexpr size_t OFF_AC = OFF_BS + 8192;                        // accW[4096][32], accO[4096][32]
static constexpr size_t ACC_HALF = (size_t)32 * B_N * 4;               // 512 KB
static constexpr size_t OFF_CS = OFF_AC + 2 * ACC_HALF;                // f32 [4096][512]
static constexpr size_t WS_NEED = OFF_CS + (size_t)B_N * H_N * 4;      // ~36 MB

__device__ __forceinline__ short hfbits(float x) {
    union { _Float16 h; short s; } v; v.h = (_Float16)x; return v.s;
}
__device__ __forceinline__ float sigmoidf_(float x) { return 1.f / (1.f + __expf(-x)); }
__device__ __forceinline__ float tanhf_(float x) {
    float ax = fabsf(x), e = __expf(-2.f * ax);
    float t = (1.f - e) / (1.f + e);
    return x < 0.f ? -t : t;
}

__global__ __launch_bounds__(256) void fill_out(float* out, float v) {
    int i = blockIdx.x * 256 + threadIdx.x;
    if (i < B_N * 32) out[i] = v;
}

// ---------------- prep_x: x-in-registers + stencil shuffles + scalar weights ----------------
__global__ __launch_bounds__(256) void prep_x(const float* __restrict__ input,
                       const float* __restrict__ mask,
                       const float* __restrict__ w1, const float* __restrict__ b1,
                       const float* __restrict__ cw, const float* __restrict__ cb,
                       float* __restrict__ x, float* __restrict__ ua)
{
    __shared__ float sin[8 * L_N * XS];
    __shared__ float sxb[8 * L_N * XS];
    const float* src = input + (size_t)blockIdx.x * (8 * L_N * C_N);
    for (int i = threadIdx.x; i < 8 * L_N * C_N; i += 256) {
        int lr = i / (L_N * C_N);
        int rem = i - lr * (L_N * C_N);
        int l = rem / C_N, c = rem - l * C_N;
        sin[lr * (L_N * XS) + l * XS + c] = src[i];
    }
    __syncthreads();

    int idx = blockIdx.x * 256 + threadIdx.x;
    int l = idx & 31;
    int wv = threadIdx.x >> 5;
    const float* inb = sin + wv * (L_N * XS);
    float m = mask[idx];

    float x0r[C_N], xm1[C_N], xp1[C_N];
    #pragma unroll
    for (int i = 0; i < C_N; ++i) x0r[i] = inb[l * XS + i];
    #pragma unroll
    for (int i = 0; i < C_N; ++i) {
        float up = __shfl_up(x0r[i], 1, 32);
        float dn = __shfl_down(x0r[i], 1, 32);
        xm1[i] = (l > 0)  ? up : 0.f;
        xp1[i] = (l < 31) ? dn : 0.f;
    }

    float uacc = 0.f;
    float* sxrow = sxb + wv * (L_N * XS) + l * XS;
    #pragma unroll 2
    for (int o = 0; o < C_N; ++o) {
        const float* wo = w1 + o * (C_N * 3);   // wave-uniform -> s_load
        float y0 = b1[o], y1 = 0.f, y2 = 0.f;
        #pragma unroll
        for (int i = 0; i < C_N; ++i) {
            y0 += wo[i * 3 + 0] * xm1[i];
            y1 += wo[i * 3 + 1] * x0r[i];
            y2 += wo[i * 3 + 2] * xp1[i];
        }
        float y = (y0 + y1 + y2) * m;
        float e = (y > 0.f) ? y : (__expf(y) - 1.f);
        float xv = e + inb[l * XS + o];
        sxrow[o] = xv;
        uacc += xv * cw[o];
    }
    ua[idx] = (uacc + cb[0]) * m;
    __syncthreads();
    float* xdst = x + (size_t)blockIdx.x * (8 * L_N * C_N);
    for (int i = threadIdx.x; i < 8 * L_N * C_N; i += 256) {
        int lr = i / (L_N * C_N);
        int rem = i - lr * (L_N * C_N);
        int l2 = rem / C_N, c = rem - l2 * C_N;
        xdst[i] = sxb[lr * (L_N * XS) + l2 * XS + c];
    }
}

// ---------------- prep_wf: frag-major SINGLE-fp16 weights, gate-in-tile packing ----------------
__global__ __launch_bounds__(256) void prep_wf(const float* __restrict__ w_ih,
                                               const float* __restrict__ w_hh,
                                               short* __restrict__ Wf)
{
    int blk = blockIdx.x;                  // 16*17
    int n128 = blk / 17, c = blk % 17;
    int kbase = c * 32;
    short* dst = Wf + ((size_t)n128 * CHA + c) * CHSH;
    for (int g = threadIdx.x; g < 512; g += 256) {
        int j = g >> 6, lane = g & 63;
        int gate = j & 3;
        int unit = n128 * 32 + (j >> 2) * 16 + (lane & 15);
        int srow = gate * H_N + unit;
        int kg = lane >> 4;
        s16x8 out;
        #pragma unroll
        for (int b2 = 0; b2 < 8; ++b2) {
            int k = kbase + kg * 8 + b2;
            float v = 0.f;
            if (k < 512) v = w_hh[(size_t)srow * H_N + k];
            else if (k < 540) v = w_ih[srow * C_N + (k - 512)];
            out[b2] = hfbits(v);
        }
        *(s16x8*)(dst + g * 8) = out;
    }
}

__global__ void prep_bs(const float* __restrict__ b_ih, const float* __restrict__ b_hh,
                        float* __restrict__ bsum)
{
    int p = blockIdx.x * 256 + threadIdx.x;
    if (p < G_N) {
        int unit = p >> 2, gate = p & 3;
        bsum[p] = b_ih[gate * H_N + unit] + b_hh[gate * H_N + unit];
    }
}

__global__ void prep_zero(unsigned int* __restrict__ a32, float* __restrict__ cst,
                          float* __restrict__ acc)
{
    int idx = blockIdx.x * blockDim.x + threadIdx.x;
    if (idx < B_N * 1088) a32[idx] = 0u;
    if (idx < B_N * H_N) cst[idx] = 0.f;
    if (idx < 2 * 32 * B_N) acc[idx] = 0.f;
}

// ---------------- params ----------------
struct RParams {
    const float* mask;
    const float* bias_mat;
    const float* fc1_w;
    const float* fc1_b;
    const float* conv2_w;
    const float* conv2_b;
    const short* Wf;
    const short* Ain;
    short* Aout;
    const float* x;
    const float* ua;
    const float* bsum;
    float* accW;           // [4096][32] slot = n*2+wn
    float* accO;           // [4096][32]
    float* cstate;
    float* out;
};

// ---------------- ctx_step: sum 32 partial slots; softmax+context (LDS-staged x) ----------------
__global__ __launch_bounds__(256) void ctx_step(RParams P, int t)
{
    __shared__ float sx[4][L_N * C_N];

    const int lane = threadIdx.x & 63;
    const int wave = threadIdx.x >> 6;
    const int row  = blockIdx.x * 4 + wave;

    f32x2 st[7];
    const float* xrow = P.x + (size_t)row * (L_N * C_N);
    #pragma unroll
    for (int q = 0; q < 7; ++q) st[q] = *(const f32x2*)(xrow + (q * 64 + lane) * 2);

    float v = (lane < 32) ? P.accW[row * 32 + lane] : P.accO[row * 32 + (lane - 32)];
    #pragma unroll
    for (int off = 1; off <= 16; off <<= 1) v += __shfl_xor(v, off);
    float aW = __shfl(v, 0);
    float aO = __shfl(v, 32);

    if (t > 0 && lane == 0)
        P.out[row * T_N + (t - 1)] = (aO + P.conv2_b[0]) * P.mask[row * L_N + (t - 1)];

    if (t < T_N) {
        float w_a = aW + P.fc1_b[0];
        int l32 = lane & 31;
        float e = P.ua[row * L_N + l32] + w_a;
        e = (e > 0.f) ? e : 0.01f * e;
        e += P.bias_mat[row * L_N + l32];
        float mx = e;
        #pragma unroll
        for (int off = 16; off > 0; off >>= 1) mx = fmaxf(mx, __shfl_xor(mx, off, 32));
        float pexp = __expf(e - mx);
        float ssum = pexp;
        #pragma unroll
        for (int off = 16; off > 0; off >>= 1) ssum += __shfl_xor(ssum, off, 32);
        float p = pexp / ssum;

        #pragma unroll
        for (int q = 0; q < 7; ++q)
            *(f32x2*)(&sx[wave][(q * 64 + lane) * 2]) = st[q];

        int cc = (lane < C_N) ? lane : 0;
        float ctx = 0.f;
        #pragma unroll
        for (int l = 0; l < L_N; ++l) {
            float al = __shfl(p, l);
            ctx += al * sx[wave][l * C_N + cc];
        }
        if (lane < C_N) {
            int m128 = row >> 7, mt = (row & 127) >> 4, r = row & 15;
            int flane = r + 16 * (lane >> 3);
            short* base = P.Aout + (size_t)m128 * ABLK + mt * 512 + flane * 8 + (lane & 7);
            _Float16 hi = (_Float16)ctx;
            union { _Float16 h; short s; } uh; uh.h = hi;
            base[16 * CHSH] = uh.s;
            base[33 * CHSH] = hfbits(ctx - (float)hi);
        }
    }
}

// ---------------- gemm_cell_step: M=128, paired k-steps, fp16, SGB ----------------
// Buffer (24KB): [A_hi 8K | A_lo 8K | W 8K]; bufp0=even chunks, bufp1=odd.
// Step: vmcnt(0)+bar -> 24 ds_read -> lgkmcnt(0)+bar -> stage next pair + 64 MFMA.
#define STG_BUF 24576

__global__ __launch_bounds__(256, 2) void gemm_cell_step(RParams P)
{
    __shared__ __align__(16) char smem[49152];

    const int tid  = threadIdx.x;
    const int lane = tid & 63;
    const int wave = tid >> 6;
    const int bid  = blockIdx.x;       // 512
    const int xg = bid & 7, gg = bid >> 3;
    const int m  = (xg >> 1) * 8 + (gg & 7);
    const int n  = (xg & 1) * 8 + (gg >> 3);
    const int wm = wave >> 1, wn = wave & 1;

    const short* Af = P.Ain + (size_t)m * ABLK;
    const short* Wg = P.Wf  + (size_t)n * ABLK;

    char* bufp0 = smem;
    char* bufp1 = smem + STG_BUF;

    auto stage = [&](char* lbuf, int kk) {
        const short* pAh = Af + (size_t)kk * CHSH;
        const short* pAl = Af + (size_t)(17 + kk) * CHSH;
        const short* pW  = Wg + (size_t)kk * CHSH;
        #pragma unroll
        for (int i = 0; i < 6; ++i) {
            int r = wave * 6 + i;
            const short* base = (r < 8)  ? (pAh + r * 512)
                              : (r < 16) ? (pAl + (r - 8) * 512)
                                         : (pW + (r - 16) * 512);
            __builtin_amdgcn_global_load_lds(
                (const __attribute__((address_space(1))) void*)(base + lane * 8),
                (__attribute__((address_space(3))) void*)(lbuf + r * 1024),
                16, 0, 0);
        }
    };

    int aoff[4], woff[4];
    #pragma unroll
    for (int i = 0; i < 4; ++i) {
        aoff[i] = ((wm * 4 + i) * 64 + lane) * 16;
        woff[i] = ((wn * 4 + i) * 64 + lane) * 16;
    }

    f32x4 acc[4][4];
    #pragma unroll
    for (int i = 0; i < 4; ++i)
        #pragma unroll
        for (int j = 0; j < 4; ++j)
            acc[i][j] = (f32x4){0.f, 0.f, 0.f, 0.f};

    // R[0..3]=A_hi, R[4..7]=A_lo, R[8..11]=W
    f16x8 R0[12], R1[12];
    auto ldfr = [&](const char* b, f16x8 (&R)[12]) {
        #pragma unroll
        for (int i = 0; i < 4; ++i) {
            R[i]     = *(const f16x8*)(b + aoff[i]);
            R[4 + i] = *(const f16x8*)(b + 8192 + aoff[i]);
            R[8 + i] = *(const f16x8*)(b + 16384 + woff[i]);
        }
    };
    auto domm = [&](f16x8 (&R)[12]) {
        #pragma unroll
        for (int i = 0; i < 4; ++i)
            #pragma unroll
            for (int j = 0; j < 4; ++j)
                acc[i][j] = __builtin_amdgcn_mfma_f32_16x16x32_f16(R[i], R[8 + j], acc[i][j], 0, 0, 0);
        #pragma unroll
        for (int i = 0; i < 4; ++i)
            #pragma unroll
            for (int j = 0; j < 4; ++j)
                acc[i][j] = __builtin_amdgcn_mfma_f32_16x16x32_f16(R[4 + i], R[8 + j], acc[i][j], 0, 0, 0);
    };

    // paired step: phase1 = 24 ds_read (both buffers); phase2 = stage next pair
    // (12 or 6 VMEM) interleaved with 64 MFMA via SGB. nstage: 2, 1, or 0.
    auto step_pair = [&](int c0, int nstage) {
        asm volatile("s_waitcnt vmcnt(0) lgkmcnt(0)" ::: "memory");
        __builtin_amdgcn_s_barrier();
        __builtin_amdgcn_sched_barrier(0);
        ldfr(bufp0, R0);
        ldfr(bufp1, R1);
        asm volatile("s_waitcnt lgkmcnt(0)" ::: "memory");
        __builtin_amdgcn_sched_barrier(0);       // rule #18: reads sealed here
        __builtin_amdgcn_s_barrier();            // all waves' reads done -> overwrite ok
        __builtin_amdgcn_sched_barrier(0);
        if (nstage >= 1) stage(bufp0, c0 + 2);
        if (nstage >= 2) stage(bufp1, c0 + 3);
        domm(R0);
        domm(R1);
        if (nstage == 2) {
            #pragma unroll
            for (int g = 0; g < 12; ++g) {
                __builtin_amdgcn_sched_group_barrier(0x010, 1, 0);  // 1 VMEM
                __builtin_amdgcn_sched_group_barrier(0x008, 5, 0);  // 5 MFMA
            }
            __builtin_amdgcn_sched_group_barrier(0x008, 4, 0);      // remaining 4
        } else if (nstage == 1) {
            #pragma unroll
            for (int g = 0; g < 6; ++g) {
                __builtin_amdgcn_sched_group_barrier(0x010, 1, 0);
                __builtin_amdgcn_sched_group_barrier(0x008, 8, 0);
            }
            __builtin_amdgcn_sched_group_barrier(0x008, 16, 0);
        }
        __builtin_amdgcn_sched_barrier(0);
    };
    // final single chunk (16) from bufp0
    auto step_single = [&]() {
        asm volatile("s_waitcnt vmcnt(0) lgkmcnt(0)" ::: "memory");
        __builtin_amdgcn_s_barrier();
        __builtin_amdgcn_sched_barrier(0);
        ldfr(bufp0, R0);
        domm(R0);
        __builtin_amdgcn_sched_barrier(0);
    };

    stage(bufp0, 0);
    stage(bufp1, 1);

    for (int s = 0; s < 7; ++s)
        step_pair(2 * s, 2);          // chunks 0..13, stage 2..15
    step_pair(14, 1);                 // chunks 14,15; stage chunk 16 -> bufp0
    step_single();                    // chunk 16

    // ---- epilogue (in-register LSTM: thread owns unit = n*32+wn*16+(lane&15)) ----
    __syncthreads();
    short* hasm = (short*)smem;              // hi 8KB @0, lo 8KB @8192
    {
        int u15 = lane & 15, rq = lane >> 4;
        int unit = n * 32 + wn * 16 + u15;
        float cpre[4][4];
        #pragma unroll
        for (int i = 0; i < 4; ++i)
            #pragma unroll
            for (int r = 0; r < 4; ++r)
                cpre[i][r] = P.cstate[(size_t)(m * 128 + wm * 64 + i * 16 + rq * 4 + r) * H_N + unit];
        f32x4 bsv = *(const f32x4*)(P.bsum + unit * 4);
        float f1v = P.fc1_w[unit];
        float c2v = P.conv2_w[unit];
        const int fl16 = 16 * (wn * 2 + (u15 >> 3));
        const int slot = u15 & 7;
        #pragma unroll
        for (int i = 0; i < 4; ++i) {
            #pragma unroll
            for (int r = 0; r < 4; ++r) {
                int grow = m * 128 + wm * 64 + i * 16 + rq * 4 + r;
                float pi = acc[i][0][r] + bsv.x;
                float pf = acc[i][1][r] + bsv.y;
                float pg = acc[i][2][r] + bsv.z;
                float po = acc[i][3][r] + bsv.w;
                float c = sigmoidf_(pf) * cpre[i][r] + sigmoidf_(pi) * tanhf_(pg);
                P.cstate[(size_t)grow * H_N + unit] = c;
                float h = sigmoidf_(po) * tanhf_(c);
                _Float16 hh = (_Float16)h;
                union { _Float16 hf; short s; } uh; uh.hf = hh;
                int fo = (wm * 4 + i) * 512 + (rq * 4 + r + fl16) * 8 + slot;
                hasm[fo]        = uh.s;
                hasm[4096 + fo] = hfbits(h - (float)hh);
                float wd = f1v * h, od = c2v * h;
                #pragma unroll
                for (int off = 8; off > 0; off >>= 1) {
                    wd += __shfl_xor(wd, off);
                    od += __shfl_xor(od, off);
                }
                if (u15 == 0) {
                    P.accW[(size_t)grow * 32 + (n * 2 + wn)] = wd;
                    P.accO[(size_t)grow * 32 + (n * 2 + wn)] = od;
                }
            }
        }
    }
    __syncthreads();
    short* dhi = P.Aout + (size_t)m * ABLK + (size_t)n * CHSH;
    short* dlo = P.Aout + (size_t)m * ABLK + (size_t)(17 + n) * CHSH;
    *(s16x8*)(dhi + tid * 16)     = *(const s16x8*)(hasm + tid * 16);
    *(s16x8*)(dhi + tid * 16 + 8) = *(const s16x8*)(hasm + tid * 16 + 8);
    *(s16x8*)(dlo + tid * 16)     = *(const s16x8*)(hasm + 4096 + tid * 16);
    *(s16x8*)(dlo + tid * 16 + 8) = *(const s16x8*)(hasm + 4096 + tid * 16 + 8);
}

extern "C" void kernel_launch(void* const* d_in, const int* in_sizes, int n_in,
                              void* d_out, int out_size, void* d_ws, size_t ws_size,
                              hipStream_t stream)
{
    float* out = (float*)d_out;
    if (ws_size < WS_NEED) { fill_out<<<512, 256, 0, stream>>>(out, 4000.f); return; }

    const float* input = (const float*)d_in[0];
    const float* mask  = (const float*)d_in[1];
    const float* biasm = (const float*)d_in[2];
    const float* w1    = (const float*)d_in[3];
    const float* b1    = (const float*)d_in[4];
    const float* cw    = (const float*)d_in[5];
    const float* cb    = (const float*)d_in[6];
    const float* w_ih  = (const float*)d_in[7];
    const float* w_hh  = (const float*)d_in[8];
    const float* b_ih  = (const float*)d_in[9];
    const float* b_hh  = (const float*)d_in[10];
    const float* fc1w  = (const float*)d_in[11];
    const float* fc1b  = (const float*)d_in[12];
    const float* c2w   = (const float*)d_in[13];
    const float* c2b   = (const float*)d_in[14];

    char* ws = (char*)d_ws;
    short* Wf = (short*)(ws + OFF_WF);
    short* A0 = (short*)(ws + OFF_AB);
    short* A1 = (short*)(ws + OFF_AB + AB_ONE);
    float* x    = (float*)(ws + OFF_X);
    float* ua   = (float*)(ws + OFF_UA);
    float* bsum = (float*)(ws + OFF_BS);
    float* accW = (float*)(ws + OFF_AC);
    float* accO = (float*)(ws + OFF_AC + ACC_HALF);
    float* cst  = (float*)(ws + OFF_CS);

    prep_x<<<(B_N * L_N) / 256, 256, 0, stream>>>(input, mask, w1, b1, cw, cb, x, ua);
    prep_wf<<<16 * 17, 256, 0, stream>>>(w_ih, w_hh, Wf);
    prep_bs<<<(G_N + 255) / 256, 256, 0, stream>>>(b_ih, b_hh, bsum);
    prep_zero<<<(B_N * 1088 + 255) / 256, 256, 0, stream>>>((unsigned int*)A0, cst, accW);

    RParams P;
    P.mask = mask; P.bias_mat = biasm; P.fc1_w = fc1w; P.fc1_b = fc1b;
    P.conv2_w = c2w; P.conv2_b = c2b; P.Wf = Wf;
    P.x = x; P.ua = ua; P.bsum = bsum; P.accW = accW; P.accO = accO;
    P.cstate = cst; P.out = out;

    short* bufs[2] = { A0, A1 };
    for (int t = 0; t < T_N; ++t) {
        P.Ain  = bufs[t & 1];
        P.Aout = bufs[t & 1];
        ctx_step<<<B_N / 4, 256, 0, stream>>>(P, t);
        P.Ain  = bufs[t & 1];
        P.Aout = bufs[(t + 1) & 1];
        gemm_cell_step<<<512, 256, 0, stream>>>(P);
    }
    P.Ain = bufs[T_N & 1];
    P.Aout = bufs[T_N & 1];
    ctx_step<<<B_N / 4, 256, 0, stream>>>(P, T_N);
}